// Round 12
// baseline (256.133 us; speedup 1.0000x reference)
//
#include <hip/hip_runtime.h>
#include <stdint.h>
#include <math.h>

typedef __attribute__((ext_vector_type(8))) short bf16x8;
typedef __attribute__((ext_vector_type(4))) short v4s;
typedef __attribute__((ext_vector_type(4))) float f32x4;
typedef __attribute__((ext_vector_type(4))) unsigned short u16x4;
typedef __attribute__((ext_vector_type(2))) unsigned int u32x2;

#define MFMA16(a,b,c)   __builtin_amdgcn_mfma_f32_16x16x32_bf16((a),(b),(c),0,0,0)
#define MFMA16K(a,b,c)  __builtin_amdgcn_mfma_f32_16x16x16bf16_1k((a),(b),(c),0,0,0)

static __device__ __forceinline__ void gld_lds16(const void* g, void* l) {
  __builtin_amdgcn_global_load_lds(
      (const __attribute__((address_space(1))) unsigned int*)g,
      (__attribute__((address_space(3))) unsigned int*)l,
      16, 0, 0);
}

static __device__ __forceinline__ unsigned short f2bf(float f) {
  unsigned int u = __builtin_bit_cast(unsigned int, f);
  return (unsigned short)((u + 0x8000u) >> 16);
}

// fp32 -> bf16, grid-stride, float4 loads.
__global__ __launch_bounds__(256) void cvt_kernel(const float* __restrict__ in,
                                                  unsigned short* __restrict__ out,
                                                  int n4) {
  int i = blockIdx.x * blockDim.x + threadIdx.x;
  int stride = gridDim.x * blockDim.x;
  for (; i < n4; i += stride) {
    float4 v = ((const float4*)in)[i];
    u16x4 o;
    o.x = f2bf(v.x); o.y = f2bf(v.y); o.z = f2bf(v.z); o.w = f2bf(v.w);
    ((u16x4*)out)[i] = o;
  }
}

__global__ __launch_bounds__(256) void cvt4_kernel(const float* __restrict__ w0,
                                                   const float* __restrict__ w1,
                                                   const float* __restrict__ w2,
                                                   const float* __restrict__ w3,
                                                   unsigned short* __restrict__ out) {
  const float* in = (blockIdx.y == 0) ? w0 : (blockIdx.y == 1) ? w1
                  : (blockIdx.y == 2) ? w2 : w3;
  unsigned short* o = out + (size_t)blockIdx.y * 1048576;
  int i = blockIdx.x * blockDim.x + threadIdx.x;
  int stride = gridDim.x * blockDim.x;
  for (; i < 1048576/4; i += stride) {
    float4 v = ((const float4*)in)[i];
    u16x4 t;
    t.x = f2bf(v.x); t.y = f2bf(v.y); t.z = f2bf(v.z); t.w = f2bf(v.w);
    ((u16x4*)o)[i] = t;
  }
}

// FUSED QKV: one block computes the Q, K AND V 128x128 output tiles for its
// (m0,n0), sharing a single X staging. Rationale (r11 post-mortem): the
// stage->vmcnt(0)-drain is the critical path (T2 swizzle zeroed 6.3M bank
// conflicts with NO timing change); per-thread DMA issue count per barrier is
// unchanged (4: 1 X + 3 W vs 2 A + 2 B) but compute per drain triples
// (192 vs 64 block-MFMA), X is staged once not 3x (LDS-DMA 786->524 MB),
// and block count drops 1536->512.
// 512 threads = 8 waves: wave w owns the 32x64 quadrant (wm=w>>1, wn=w&1) of
// each GEMM's tile; acc = 3 x 8 x f32x4 = 96 regs. __launch_bounds__(512,2)
// -> 256-reg cap, 1 block/CU, LDS 32KB.
// T2 chunk swizzle as r11 (validated: 0 conflicts): stage global chunk
// q^((r>>1)&3) at linear chunk q; read chunk quad^((c0>>1)&3).
// Outputs: Q MODE3 (head-split, pre-scaled log2(e)/8), K MODE0, V MODE2 (transposed).
__global__ __launch_bounds__(512, 2) void qkv_fused_kernel(
    const unsigned short* __restrict__ X,
    const unsigned short* __restrict__ WQ, const unsigned short* __restrict__ WK,
    const unsigned short* __restrict__ WV,
    unsigned short* __restrict__ Q, unsigned short* __restrict__ K,
    unsigned short* __restrict__ V)
{
  __shared__ __align__(16) unsigned short Xs[128*32];
  __shared__ __align__(16) unsigned short Ws0[128*32];
  __shared__ __align__(16) unsigned short Ws1[128*32];
  __shared__ __align__(16) unsigned short Ws2[128*32];

  const int tid  = threadIdx.x;
  const int w    = tid >> 6, lane = tid & 63;
  const int quad = lane >> 4, c0 = lane & 15;
  const int wm   = w >> 1, wn = w & 1;
  const int m0 = blockIdx.x * 128, n0 = blockIdx.y * 128;

  // staging: 8KB per segment, 1 x 16B chunk per thread per segment.
  const int r  = tid >> 2, q = tid & 3;
  const int gq = q ^ ((r >> 1) & 3);            // T2 swizzle, source side
  const unsigned short* gx  = X  + (m0 + r)*1024 + gq*8;
  const unsigned short* gw0 = WQ + (n0 + r)*1024 + gq*8;
  const unsigned short* gw1 = WK + (n0 + r)*1024 + gq*8;
  const unsigned short* gw2 = WV + (n0 + r)*1024 + gq*8;
  const int lb = w * 1024;                      // wave-uniform LDS dest offset

  int aAddr[2], bAddr[4];
  const int sq = (quad ^ ((c0 >> 1) & 3)) * 16; // T2 swizzle, read side
  #pragma unroll
  for (int t = 0; t < 2; ++t) aAddr[t] = (wm*32 + t*16 + c0)*64 + sq;
  #pragma unroll
  for (int t = 0; t < 4; ++t) bAddr[t] = (wn*64 + t*16 + c0)*64 + sq;

  f32x4 aQ[2][4], aK[2][4], aV[2][4];
  #pragma unroll
  for (int i = 0; i < 2; ++i)
    #pragma unroll
    for (int j = 0; j < 4; ++j) {
      aQ[i][j] = (f32x4){0.f, 0.f, 0.f, 0.f};
      aK[i][j] = (f32x4){0.f, 0.f, 0.f, 0.f};
      aV[i][j] = (f32x4){0.f, 0.f, 0.f, 0.f};
    }

  for (int kt = 0; kt < 32; ++kt) {
    __syncthreads();
    gld_lds16(gx  + kt*32, (char*)Xs  + lb);
    gld_lds16(gw0 + kt*32, (char*)Ws0 + lb);
    gld_lds16(gw1 + kt*32, (char*)Ws1 + lb);
    gld_lds16(gw2 + kt*32, (char*)Ws2 + lb);
    __syncthreads();

    bf16x8 af[2], bq[4], bk[4], bv[4];
    #pragma unroll
    for (int t = 0; t < 2; ++t) af[t] = *(const bf16x8*)((const char*)Xs  + aAddr[t]);
    #pragma unroll
    for (int t = 0; t < 4; ++t) bq[t] = *(const bf16x8*)((const char*)Ws0 + bAddr[t]);
    #pragma unroll
    for (int t = 0; t < 4; ++t) bk[t] = *(const bf16x8*)((const char*)Ws1 + bAddr[t]);
    #pragma unroll
    for (int t = 0; t < 4; ++t) bv[t] = *(const bf16x8*)((const char*)Ws2 + bAddr[t]);

    #pragma unroll
    for (int mt = 0; mt < 2; ++mt)
      #pragma unroll
      for (int nt = 0; nt < 4; ++nt) {
        aQ[mt][nt] = MFMA16(af[mt], bq[nt], aQ[mt][nt]);
        aK[mt][nt] = MFMA16(af[mt], bk[nt], aK[mt][nt]);
        aV[mt][nt] = MFMA16(af[mt], bv[nt], aV[mt][nt]);
      }
  }

  const float scl = 0.1803368801f;  // log2(e)/8
  #pragma unroll
  for (int mt = 0; mt < 2; ++mt) {
    #pragma unroll
    for (int nt = 0; nt < 4; ++nt) {
      int gc = n0 + wn*64 + nt*16 + c0;
      int hh = gc >> 6, d = gc & 63;
      // Q (scaled) and K: head-split [b,h,s,64]
      #pragma unroll
      for (int r4 = 0; r4 < 4; ++r4) {
        int gr = m0 + wm*32 + mt*16 + quad*4 + r4;
        int b = gr >> 11, s = gr & 2047;
        size_t base = ((size_t)(((b << 4) + hh)*2048 + s))*64 + d;
        Q[base] = f2bf(aQ[mt][nt][r4] * scl);
        K[base] = f2bf(aK[mt][nt][r4]);
      }
      // V transposed: [b,h,64,s], 4 consecutive s per u16x4
      u16x4 pk;
      #pragma unroll
      for (int r4 = 0; r4 < 4; ++r4) pk[r4] = f2bf(aV[mt][nt][r4]);
      int s0 = m0 + wm*32 + mt*16 + quad*4;
      int b = s0 >> 11, ss = s0 & 2047;
      *(u16x4*)(V + ((size_t)(((b << 4) + hh)*64 + d))*2048 + ss) = pk;
    }
  }
}

// C = A[M,K] * Bt[N,K]^T, A/Bt bf16, K=1024, 128x128 tile, BK=32.
// MODE 1: C fp32 row-major (used by proj only now).
// Simple stage->barrier->compute loop (dbuf regressed twice: r9 VALU tax,
// r10 conflicts+LDS). T2 chunk swizzle: 0 bank conflicts (r11 measured).
template<int MODE, typename CT>
__device__ __forceinline__ void gemm_bt_tile(const unsigned short* __restrict__ A,
                                             const unsigned short* __restrict__ Bt,
                                             CT* __restrict__ C,
                                             int m0, int n0,
                                             unsigned short* As,
                                             unsigned short* Bs)
{
  const int tid  = threadIdx.x;
  const int w    = tid >> 6, lane = tid & 63;
  const int quad = lane >> 4, c0 = lane & 15;
  const int wm   = w >> 1, wn = w & 1;

  const unsigned short* ga[2];
  const unsigned short* gb[2];
  int ldsoff[2];
  #pragma unroll
  for (int i = 0; i < 2; ++i) {
    int f = i*4096 + w*1024 + lane*16;   // byte offset in 8KB tile
    int r = f >> 6;                      // tile row (64B = 32 bf16 per row)
    int q = (f >> 4) & 3;                // 16B chunk in row
    int gq = q ^ ((r >> 1) & 3);         // T2 swizzle (inverse on source side)
    ga[i] = A  + (m0 + r)*1024 + gq*8;
    gb[i] = Bt + (n0 + r)*1024 + gq*8;
    ldsoff[i] = i*4096 + w*1024;
  }

  int aAddr[4], bAddr[4];
  const int sq = (quad ^ ((c0 >> 1) & 3)) * 16;   // swizzled chunk byte offset
  #pragma unroll
  for (int t = 0; t < 4; ++t) {
    aAddr[t] = (wm*64 + t*16 + c0)*64 + sq;
    bAddr[t] = (wn*64 + t*16 + c0)*64 + sq;
  }

  f32x4 acc[4][4];
  #pragma unroll
  for (int i = 0; i < 4; ++i)
    #pragma unroll
    for (int j = 0; j < 4; ++j)
      acc[i][j] = (f32x4){0.f, 0.f, 0.f, 0.f};

  for (int kt = 0; kt < 32; ++kt) {
    __syncthreads();
    #pragma unroll
    for (int i = 0; i < 2; ++i) {
      gld_lds16(ga[i] + kt*32, (char*)As + ldsoff[i]);
      gld_lds16(gb[i] + kt*32, (char*)Bs + ldsoff[i]);
    }
    __syncthreads();

    bf16x8 af[4], bfr[4];
    #pragma unroll
    for (int t = 0; t < 4; ++t) af[t]  = *(const bf16x8*)((const char*)As + aAddr[t]);
    #pragma unroll
    for (int t = 0; t < 4; ++t) bfr[t] = *(const bf16x8*)((const char*)Bs + bAddr[t]);

    #pragma unroll
    for (int mt = 0; mt < 4; ++mt)
      #pragma unroll
      for (int nt = 0; nt < 4; ++nt)
        acc[mt][nt] = MFMA16(af[mt], bfr[nt], acc[mt][nt]);
  }

  #pragma unroll
  for (int mt = 0; mt < 4; ++mt) {
    #pragma unroll
    for (int nt = 0; nt < 4; ++nt) {
      #pragma unroll
      for (int r = 0; r < 4; ++r) {
        int gr = m0 + wm*64 + mt*16 + quad*4 + r;
        int gc = n0 + wn*64 + nt*16 + c0;
        ((float*)C)[gr*1024 + gc] = acc[mt][nt][r];
      }
    }
  }
}

__global__ __launch_bounds__(256) void proj_kernel(
    const unsigned short* __restrict__ A,
    const unsigned short* __restrict__ WO,
    float* __restrict__ C)
{
  __shared__ __align__(16) unsigned short As[128*32];
  __shared__ __align__(16) unsigned short Bs[128*32];
  gemm_bt_tile<1>(A, WO, C, blockIdx.x*128, blockIdx.y*128, As, Bs);
}

// Flash attention, causal. Q (pre-scaled by log2e/8) / K bf16 [bh,s,64];
// V TRANSPOSED bf16 [bh,64,s]. O bf16 [b,s,1024].
// Grid (BH, 8): block y processes the qt-PAIR {15-by, by} = 17 K-tiles ->
// equal-length blocks (r6 showed unequal blocks create a dispatch tail).
// Linear id = bh + BH*y -> XCD = bh%8: all 8 blocks of one head share one
// XCD's L2 (r3 win: FETCH 143->31MB).
// __launch_bounds__(256,2): 2 waves/SIMD is the ceiling for this footprint
// ((.,4) forced 64-VGPR + ~180MB spill twice: r1, r4).
// K staged through LDS like V (r7 win: attn 84.7 -> <72us): double-buffered,
// global_load_lds issued at tile START -> full tile of compute covers the DMA
// before the barrier drains vmcnt. Source-side XOR swizzle (chunk ^= row&7,
// linear LDS dest) makes the per-body ds_read_b128 K reads bank-conflict-free.
// s_setprio(1) around each tile's MFMA+softmax cluster (T5).
__global__ __launch_bounds__(256, 2) void attn_kernel(
    const unsigned short* __restrict__ Q,
    const unsigned short* __restrict__ K,
    const unsigned short* __restrict__ Vt,
    unsigned short* __restrict__ O)
{
  __shared__ __align__(16) unsigned short VtL[2][64*128];  // V^T tiles, chunk-swizzled
  __shared__ __align__(16) unsigned short KL[2][128*64];   // K tiles, chunk-swizzled

  const int tid  = threadIdx.x;
  const int w    = tid >> 6, lane = tid & 63;
  const int quad = lane >> 4, c0 = lane & 15;
  const int bx = blockIdx.y, bh = blockIdx.x;

  const unsigned short* Qh = Q  + (size_t)bh*2048*64;
  const unsigned short* Kh = K  + (size_t)bh*2048*64;
  const unsigned short* Vh = Vt + (size_t)bh*64*2048;

  // V^T staging: LDS chunk (row r, chunk q) receives global chunk q^(r&15)
  const unsigned short* vga[4];
  // K staging: row r (128B = 8 chunks), LDS chunk (r, q) <- global chunk q^(r&7)
  const unsigned short* kga[4];
  int ldso[4];
  #pragma unroll
  for (int i = 0; i < 4; ++i) {
    int cid = i*256 + tid;
    int vr = cid >> 4, vq = cid & 15;
    vga[i] = Vh + (size_t)vr*2048 + (vq ^ (vr & 15))*8;
    int kr = cid >> 3, kq = cid & 7;
    kga[i] = Kh + (size_t)kr*64 + (kq ^ (kr & 7))*8;
    ldso[i] = i*4096 + w*1024;     // linear dest, byte = cid*16
  }

  const int b = bh >> 4, h = bh & 15;

  #define ATTN_MK_BODY(mk, Kb, Vb, DIAG)                                          \
  {                                                                               \
    bf16x8 ka0 = *(const bf16x8*)((const char*)(Kb) + ((mk)*16 + c0)*128          \
                                  + (((0*4 + quad) ^ (c0 & 7)) * 16));            \
    bf16x8 ka1 = *(const bf16x8*)((const char*)(Kb) + ((mk)*16 + c0)*128          \
                                  + (((1*4 + quad) ^ (c0 & 7)) * 16));            \
    f32x4 s0 = (f32x4){0.f,0.f,0.f,0.f}, s1 = (f32x4){0.f,0.f,0.f,0.f};           \
    s0 = MFMA16(ka0, qf[0][0], s0);                                               \
    s1 = MFMA16(ka0, qf[1][0], s1);                                               \
    s0 = MFMA16(ka1, qf[0][1], s0);                                               \
    s1 = MFMA16(ka1, qf[1][1], s1);                                               \
    if (DIAG) {                                                                   \
      _Pragma("unroll")                                                           \
      for (int r = 0; r < 4; ++r) {                                               \
        int kk = (mk)*16 + quad*4 + r;                                            \
        if (kk > w*32 + c0)      s0[r] = -1e30f;                                  \
        if (kk > w*32 + 16 + c0) s1[r] = -1e30f;                                  \
      }                                                                           \
    }                                                                             \
    float p00 = __builtin_amdgcn_exp2f(s0[0]), p01 = __builtin_amdgcn_exp2f(s0[1]); \
    float p02 = __builtin_amdgcn_exp2f(s0[2]), p03 = __builtin_amdgcn_exp2f(s0[3]); \
    float p10 = __builtin_amdgcn_exp2f(s1[0]), p11 = __builtin_amdgcn_exp2f(s1[1]); \
    float p12 = __builtin_amdgcn_exp2f(s1[2]), p13 = __builtin_amdgcn_exp2f(s1[3]); \
    l_r[0] += (p00 + p01) + (p02 + p03);                                          \
    l_r[1] += (p10 + p11) + (p12 + p13);                                          \
    u32x2 a0, a1;                                                                 \
    a0.x = __builtin_amdgcn_perm(__builtin_bit_cast(unsigned int, p01),           \
                                 __builtin_bit_cast(unsigned int, p00), 0x07060302u); \
    a0.y = __builtin_amdgcn_perm(__builtin_bit_cast(unsigned int, p03),           \
                                 __builtin_bit_cast(unsigned int, p02), 0x07060302u); \
    a1.x = __builtin_amdgcn_perm(__builtin_bit_cast(unsigned int, p11),           \
                                 __builtin_bit_cast(unsigned int, p10), 0x07060302u); \
    a1.y = __builtin_amdgcn_perm(__builtin_bit_cast(unsigned int, p13),           \
                                 __builtin_bit_cast(unsigned int, p12), 0x07060302u); \
    v4s pa0 = __builtin_bit_cast(v4s, a0);                                        \
    v4s pa1 = __builtin_bit_cast(v4s, a1);                                        \
    _Pragma("unroll")                                                             \
    for (int dt = 0; dt < 4; ++dt) {                                              \
      int vr = dt*16 + c0;                                                        \
      int p  = 2*(mk) + (quad >> 1);                                              \
      v4s vb = *(const v4s*)((const char*)(Vb) + vr*256 + ((p ^ c0) * 16) + (quad & 1)*8); \
      o_[0][dt] = MFMA16K(pa0, vb, o_[0][dt]);                                    \
      o_[1][dt] = MFMA16K(pa1, vb, o_[1][dt]);                                    \
    }                                                                             \
  }

  for (int pi = 0; pi < 2; ++pi) {
    const int qt = pi ? bx : 15 - bx;

    // Q B-frags: B[n=q=c0][k=d=quad*8+j]
    bf16x8 qf[2][2];
    #pragma unroll
    for (int mq = 0; mq < 2; ++mq)
      #pragma unroll
      for (int ks = 0; ks < 2; ++ks)
        qf[mq][ks] = *(const bf16x8*)(Qh + (qt*128 + w*32 + mq*16 + c0)*64 + ks*32 + quad*8);

    f32x4 o_[2][4];
    float l_r[2] = {0.f, 0.f};
    #pragma unroll
    for (int mq = 0; mq < 2; ++mq)
      #pragma unroll
      for (int dt = 0; dt < 4; ++dt) o_[mq][dt] = (f32x4){0.f, 0.f, 0.f, 0.f};

    __syncthreads();   // prior pass's LDS readers done
    #pragma unroll
    for (int i = 0; i < 4; ++i) {
      gld_lds16(vga[i], (char*)VtL[0] + ldso[i]);
      gld_lds16(kga[i], (char*)KL[0]  + ldso[i]);
    }

    for (int kt = 0; kt < qt; ++kt) {
      __syncthreads();   // drains V+K DMA for kt; readers of buf[(kt+1)&1] done
      #pragma unroll
      for (int i = 0; i < 4; ++i) {
        gld_lds16(vga[i] + (kt+1)*128,  (char*)VtL[(kt+1)&1] + ldso[i]);
        gld_lds16(kga[i] + (kt+1)*8192, (char*)KL[(kt+1)&1]  + ldso[i]);
      }
      const unsigned short* Vb = VtL[kt & 1];
      const unsigned short* Kb = KL[kt & 1];
      __builtin_amdgcn_s_setprio(1);
      #pragma unroll
      for (int mk = 0; mk < 8; ++mk)
        ATTN_MK_BODY(mk, Kb, Vb, false)
      __builtin_amdgcn_s_setprio(0);
    }

    // diagonal tile: mask; skip fully-masked k-blocks (wave w needs mk < 2w+2)
    {
      __syncthreads();
      const unsigned short* Vb = VtL[qt & 1];
      const unsigned short* Kb = KL[qt & 1];
      __builtin_amdgcn_s_setprio(1);
      #pragma unroll
      for (int mk = 0; mk < 8; ++mk)
        if (mk < 2*w + 2)
          ATTN_MK_BODY(mk, Kb, Vb, true)
      __builtin_amdgcn_s_setprio(0);
    }

    // reduce l across quads; epilogue
    #pragma unroll
    for (int mq = 0; mq < 2; ++mq) {
      l_r[mq] += __shfl_xor(l_r[mq], 16);
      l_r[mq] += __shfl_xor(l_r[mq], 32);
    }
    #pragma unroll
    for (int mt = 0; mt < 2; ++mt) {
      #pragma unroll
      for (int r = 0; r < 4; ++r) {
        float l = __shfl(l_r[mt], quad*4 + r);
        float inv = 1.0f / l;
        int srow = qt*128 + w*32 + mt*16 + quad*4 + r;
        #pragma unroll
        for (int dt = 0; dt < 4; ++dt) {
          int col = h*64 + dt*16 + c0;
          O[((size_t)b*2048 + srow)*1024 + col] = f2bf(o_[mt][dt][r] * inv);
        }
      }
    }
  }
  #undef ATTN_MK_BODY
}

extern "C" void kernel_launch(void* const* d_in, const int* in_sizes, int n_in,
                              void* d_out, int out_size, void* d_ws, size_t ws_size,
                              hipStream_t stream) {
  const float* xf  = (const float*)d_in[0];
  const float* wqf = (const float*)d_in[1];
  const float* wkf = (const float*)d_in[2];
  const float* wvf = (const float*)d_in[3];
  const float* wof = (const float*)d_in[4];
  float* out = (float*)d_out;
  unsigned short* ws = (unsigned short*)d_ws;

  const bool fused = ws_size >= (size_t)58720256;  // 56 MB

  if (fused) {
    unsigned short* xb  = ws;                    // 8M elems; aliased by Ow after qkv
    unsigned short* wb  = ws + 8388608;          // wq|wk|wv|wo, 1M each
    unsigned short* Kw  = ws + 12582912;
    unsigned short* Vw  = ws + 20971520;
    unsigned short* Ow  = xb;
    unsigned short* Qd  = (unsigned short*)out;  // bf16 Q scratch in fp32 out region

    cvt_kernel <<<2048, 256, 0, stream>>>(xf, xb, 8388608/4);
    cvt4_kernel<<<dim3(256, 4), 256, 0, stream>>>(wqf, wkf, wvf, wof, wb);

    qkv_fused_kernel<<<dim3(64, 8), 512, 0, stream>>>(xb, wb, wb + 1048576,
                                                      wb + 2097152, Qd, Kw, Vw);
    attn_kernel<<<dim3(64, 8),    256, 0, stream>>>(Qd, Kw, Vw, Ow);
    proj_kernel<<<dim3(64, 8),    256, 0, stream>>>(Ow, wb + 3145728, out);
  } else {
    unsigned short* xb  = ws;
    unsigned short* wb  = ws + 8388608;
    unsigned short* Kw  = ws + 12582912;
    unsigned short* Vw  = ws + 14680064;
    unsigned short* Ow  = ws + 16777216;

    cvt_kernel <<<2048, 256, 0, stream>>>(xf, xb, 8388608/4);
    cvt4_kernel<<<dim3(256, 4), 256, 0, stream>>>(wqf, wkf, wvf, wof, wb);

    for (int b = 0; b < 4; ++b) {
      const unsigned short* xbb = xb  + (size_t)b * 2048 * 1024;
      float*               outb = out + (size_t)b * 2048 * 1024;
      unsigned short*        Qd = (unsigned short*)outb;
      qkv_fused_kernel<<<dim3(16, 8), 512, 0, stream>>>(xbb, wb, wb + 1048576,
                                                        wb + 2097152, Qd, Kw, Vw);
      attn_kernel<<<dim3(16, 8),    256, 0, stream>>>(Qd, Kw, Vw, Ow);
      proj_kernel<<<dim3(16, 8),    256, 0, stream>>>(Ow, wb + 3145728, outb);
    }
  }
}